// Round 1
// baseline (57.498 us; speedup 1.0000x reference)
//
#include <hip/hip_runtime.h>

#define BB 16
#define HH 2048
#define NN 1024
#define DD 2048

// Phase 1: per-batch scores -> softmax -> scatter weighted_sum.
// One block per batch, 256 threads.
__global__ __launch_bounds__(256) void ot_phase1(const int* __restrict__ z,
                                                 const float* __restrict__ W,
                                                 float* __restrict__ wsT,
                                                 float* __restrict__ combT) {
    __shared__ int   zsh[HH];
    __shared__ float sc[HH];
    __shared__ float ws[DD];
    __shared__ float red[256];

    const int b   = blockIdx.x;
    const int tid = threadIdx.x;

    for (int h = tid; h < HH; h += 256) zsh[h] = z[b * HH + h];
    for (int d = tid; d < DD; d += 256) ws[d] = 0.f;
    __syncthreads();

    const int d1 = zsh[HH - 1];            // in [0, NN)
    const int d2 = zsh[HH - 2] + NN;       // in [NN, DD)
    const float* __restrict__ W1 = W + (size_t)d1 * DD;
    const float* __restrict__ W2 = W + (size_t)d2 * DD;

    float lmax = -1e30f;
    for (int h = tid; h < HH; h += 256) {
        int zh = zsh[h];
        float s = W1[zh] + W2[zh];
        if (h > 0) {
            int zp = zsh[h - 1] + NN;
            s += W1[zp] + W2[zp];
        }
        sc[h] = s;
        lmax = fmaxf(lmax, s);
    }
    red[tid] = lmax;
    __syncthreads();
    for (int s = 128; s > 0; s >>= 1) {
        if (tid < s) red[tid] = fmaxf(red[tid], red[tid + s]);
        __syncthreads();
    }
    const float mx = red[0];
    __syncthreads();

    float lsum = 0.f;
    for (int h = tid; h < HH; h += 256) {
        float e = expf(sc[h] - mx);
        sc[h] = e;
        lsum += e;
    }
    red[tid] = lsum;
    __syncthreads();
    for (int s = 128; s > 0; s >>= 1) {
        if (tid < s) red[tid] += red[tid + s];
        __syncthreads();
    }
    const float inv = 1.f / red[0];

    // scatter (unnormalized), normalize at write-out
    for (int h = tid; h < HH; h += 256) {
        atomicAdd(&ws[zsh[h]], sc[h]);
        if (h > 0) atomicAdd(&ws[zsh[h - 1] + NN], sc[h]);
    }
    __syncthreads();

    for (int d = tid; d < DD; d += 256) {
        float w = ws[d] * inv;
        wsT[(size_t)d * BB + b] = w;
        float c = w + ((d == d1) ? 1.f : 0.f) + ((d == d2) ? 1.f : 0.f);
        combT[(size_t)d * BB + b] = c;
    }
}

// Phase 2: xi_A = wsT^T * V[:N]^T, xi_F = combT^T * F[:N]^T, xi = xi_A + xi_F.
// One 64-lane wave per output row n; 4 waves per block; grid = NN/4.
__global__ __launch_bounds__(256) void ot_phase2(const float* __restrict__ V,
                                                 const float* __restrict__ F,
                                                 const float* __restrict__ wsT,
                                                 const float* __restrict__ combT,
                                                 float* __restrict__ out) {
    const int tid  = threadIdx.x;
    const int lane = tid & 63;
    const int n    = blockIdx.x * 4 + (tid >> 6);

    float accA[BB], accF[BB];
#pragma unroll
    for (int b = 0; b < BB; ++b) { accA[b] = 0.f; accF[b] = 0.f; }

    const float* __restrict__ Vr = V + (size_t)n * DD;
    const float* __restrict__ Fr = F + (size_t)n * DD;

    for (int i = 0; i < 8; ++i) {
        const int d = i * 256 + lane * 4;
        float4 v = *(const float4*)(Vr + d);
        float4 f = *(const float4*)(Fr + d);
#pragma unroll
        for (int k = 0; k < 4; ++k) {
            const float4* __restrict__ wp = (const float4*)(wsT   + (size_t)(d + k) * BB);
            const float4* __restrict__ cp = (const float4*)(combT + (size_t)(d + k) * BB);
            const float vk = (&v.x)[k];
            const float fk = (&f.x)[k];
#pragma unroll
            for (int q = 0; q < 4; ++q) {
                float4 w4 = wp[q];
                float4 c4 = cp[q];
                accA[q * 4 + 0] += vk * w4.x;
                accA[q * 4 + 1] += vk * w4.y;
                accA[q * 4 + 2] += vk * w4.z;
                accA[q * 4 + 3] += vk * w4.w;
                accF[q * 4 + 0] += fk * c4.x;
                accF[q * 4 + 1] += fk * c4.y;
                accF[q * 4 + 2] += fk * c4.z;
                accF[q * 4 + 3] += fk * c4.w;
            }
        }
    }

    // wave-wide reduction of all 32 accumulators
#pragma unroll
    for (int b = 0; b < BB; ++b) {
#pragma unroll
        for (int off = 32; off > 0; off >>= 1) {
            accA[b] += __shfl_down(accA[b], off);
            accF[b] += __shfl_down(accF[b], off);
        }
    }

    if (lane == 0) {
#pragma unroll
        for (int b = 0; b < BB; ++b) {
            float a  = accA[b];
            float ff = accF[b];
            out[(size_t)b * NN + n]                 = a + ff;  // xi
            out[(size_t)(BB + b) * NN + n]          = a;       // xi_A
            out[(size_t)(2 * BB + b) * NN + n]      = ff;      // xi_F
        }
    }
}

extern "C" void kernel_launch(void* const* d_in, const int* in_sizes, int n_in,
                              void* d_out, int out_size, void* d_ws, size_t ws_size,
                              hipStream_t stream) {
    const int*   z     = (const int*)d_in[0];
    const float* F_mat = (const float*)d_in[1];
    const float* V     = (const float*)d_in[2];
    const float* W     = (const float*)d_in[3];
    float* out = (float*)d_out;

    float* wsT   = (float*)d_ws;
    float* combT = wsT + (size_t)DD * BB;

    ot_phase1<<<BB, 256, 0, stream>>>(z, W, wsT, combT);
    ot_phase2<<<NN / 4, 256, 0, stream>>>(V, F_mat, wsT, combT, out);
}

// Round 2
// 34.982 us; speedup vs baseline: 1.6437x; 1.6437x over previous
//
#include <hip/hip_runtime.h>

#define BB 16
#define HH 2048
#define NN 1024
#define DD 2048

// Workspace layout: int hdr[32] (d1[16], d2[16]); pad to 128 B; then
// wsT[(DD/4)][BB][4] floats (interleaved: 4 consecutive d per b as float4).

// Phase 1: per-batch scores -> softmax -> scatter weighted_sum.
// One block per batch, 1024 threads.
__global__ __launch_bounds__(1024) void ot_phase1(const int* __restrict__ z,
                                                  const float* __restrict__ W,
                                                  int* __restrict__ hdr,
                                                  float* __restrict__ wsT) {
    __shared__ int   zsh[HH];
    __shared__ float sc[HH];
    __shared__ float ws[DD];
    __shared__ float red[1024];

    const int b   = blockIdx.x;
    const int tid = threadIdx.x;

    for (int h = tid; h < HH; h += 1024) zsh[h] = z[b * HH + h];
    for (int d = tid; d < DD; d += 1024) ws[d] = 0.f;
    __syncthreads();

    const int d1 = zsh[HH - 1];          // [0, NN)
    const int d2 = zsh[HH - 2] + NN;     // [NN, DD)
    const float* __restrict__ W1 = W + (size_t)d1 * DD;
    const float* __restrict__ W2 = W + (size_t)d2 * DD;

    float lmax = -1e30f;
    for (int h = tid; h < HH; h += 1024) {
        int zh = zsh[h];
        float s = W1[zh] + W2[zh];
        if (h > 0) {
            int zp = zsh[h - 1] + NN;
            s += W1[zp] + W2[zp];
        }
        sc[h] = s;
        lmax = fmaxf(lmax, s);
    }
    red[tid] = lmax;
    __syncthreads();
    for (int s = 512; s > 0; s >>= 1) {
        if (tid < s) red[tid] = fmaxf(red[tid], red[tid + s]);
        __syncthreads();
    }
    const float mx = red[0];
    __syncthreads();

    float lsum = 0.f;
    for (int h = tid; h < HH; h += 1024) {
        float e = __expf(sc[h] - mx);
        sc[h] = e;
        lsum += e;
    }
    red[tid] = lsum;
    __syncthreads();
    for (int s = 512; s > 0; s >>= 1) {
        if (tid < s) red[tid] += red[tid + s];
        __syncthreads();
    }
    const float inv = 1.f / red[0];

    for (int h = tid; h < HH; h += 1024) {
        atomicAdd(&ws[zsh[h]], sc[h]);
        if (h > 0) atomicAdd(&ws[zsh[h - 1] + NN], sc[h]);
    }
    __syncthreads();

    for (int d = tid; d < DD; d += 1024) {
        // interleaved layout: [d>>2][b][d&3]
        wsT[(size_t)(d >> 2) * (BB * 4) + b * 4 + (d & 3)] = ws[d] * inv;
    }
    if (tid == 0) { hdr[b] = d1; hdr[BB + b] = d2; }
}

// Phase 2: one block per output row n; 4 waves split the d dimension.
// accA[b] = sum_d V[n,d]*ws[d,b]; accF[b] = sum_d F[n,d]*ws[d,b] (+corrections).
__global__ __launch_bounds__(256) void ot_phase2(const float* __restrict__ V,
                                                 const float* __restrict__ F,
                                                 const int* __restrict__ hdr,
                                                 const float* __restrict__ wsT,
                                                 float* __restrict__ out) {
    const int tid  = threadIdx.x;
    const int lane = tid & 63;
    const int w    = tid >> 6;
    const int n    = blockIdx.x;

    const float* __restrict__ Vr = V + (size_t)n * DD;
    const float* __restrict__ Fr = F + (size_t)n * DD;

    float accA[BB], accF[BB];
#pragma unroll
    for (int b = 0; b < BB; ++b) { accA[b] = 0.f; accF[b] = 0.f; }

    // wave w owns d-groups [w*128, w*128+128); lane does 2 groups.
#pragma unroll
    for (int it = 0; it < 2; ++it) {
        const int g = w * 128 + it * 64 + lane;      // d-group (4 d's)
        float4 v = ((const float4*)Vr)[g];
        float4 f = ((const float4*)Fr)[g];
        const float4* __restrict__ wp = (const float4*)wsT + (size_t)g * BB;
#pragma unroll
        for (int b = 0; b < BB; ++b) {
            float4 s = wp[b];
            accA[b] += v.x * s.x + v.y * s.y + v.z * s.z + v.w * s.w;
            accF[b] += f.x * s.x + f.y * s.y + f.z * s.z + f.w * s.w;
        }
    }

    // wave-level reduce (lane 0 gets the sum), then cross-wave via LDS
#pragma unroll
    for (int b = 0; b < BB; ++b) {
#pragma unroll
        for (int off = 32; off > 0; off >>= 1) {
            accA[b] += __shfl_down(accA[b], off);
            accF[b] += __shfl_down(accF[b], off);
        }
    }

    __shared__ float redA[4][BB], redF[4][BB];
    if (lane == 0) {
#pragma unroll
        for (int b = 0; b < BB; ++b) { redA[w][b] = accA[b]; redF[w][b] = accF[b]; }
    }
    __syncthreads();

    if (tid < BB) {
        const int b = tid;
        float a  = redA[0][b] + redA[1][b] + redA[2][b] + redA[3][b];
        float fv = redF[0][b] + redF[1][b] + redF[2][b] + redF[3][b];
        fv += Fr[hdr[b]] + Fr[hdr[BB + b]];
        out[(size_t)b * NN + n]              = a + fv;  // xi
        out[(size_t)(BB + b) * NN + n]       = a;       // xi_A
        out[(size_t)(2 * BB + b) * NN + n]   = fv;      // xi_F
    }
}

extern "C" void kernel_launch(void* const* d_in, const int* in_sizes, int n_in,
                              void* d_out, int out_size, void* d_ws, size_t ws_size,
                              hipStream_t stream) {
    const int*   z     = (const int*)d_in[0];
    const float* F_mat = (const float*)d_in[1];
    const float* V     = (const float*)d_in[2];
    const float* W     = (const float*)d_in[3];
    float* out = (float*)d_out;

    int*   hdr = (int*)d_ws;
    float* wsT = (float*)((char*)d_ws + 128);

    ot_phase1<<<BB, 1024, 0, stream>>>(z, W, hdr, wsT);
    ot_phase2<<<NN, 256, 0, stream>>>(V, F_mat, hdr, wsT, out);
}

// Round 3
// 25.766 us; speedup vs baseline: 2.2315x; 1.3577x over previous
//
#include <hip/hip_runtime.h>

#define BB 16
#define HH 2048
#define NN 1024
#define DD 2048

// Workspace: int hdr[32] (d1[16], d2[16]); pad to 128 B; then
// wsT[DD/4][BB] float4 — float4 over 4 consecutive d, 16 batches contiguous.

// Phase 1: per-batch scores -> softmax -> scatter weighted_sum.
// One block per batch, 1024 threads (16 waves). Register softmax,
// wave-shuffle reductions, W rows staged in LDS.
__global__ __launch_bounds__(1024) void ot_phase1(const int* __restrict__ z,
                                                  const float* __restrict__ W,
                                                  int* __restrict__ hdr,
                                                  float* __restrict__ wsT) {
    __shared__ int   zsh[HH];
    __shared__ float w1s[DD];
    __shared__ float w2s[DD];
    __shared__ float ws[DD];
    __shared__ float red[16];

    const int b    = blockIdx.x;
    const int tid  = threadIdx.x;
    const int lane = tid & 63;
    const int wid  = tid >> 6;

    ((int2*)zsh)[tid] = ((const int2*)(z + (size_t)b * HH))[tid];
    ws[tid] = 0.f;
    ws[tid + 1024] = 0.f;
    __syncthreads();

    const int d1 = zsh[HH - 1];          // [0, NN)
    const int d2 = zsh[HH - 2] + NN;     // [NN, DD)

    // stage the two W rows (8 KB each) coalesced into LDS
    if (tid < 512) ((float4*)w1s)[tid]       = ((const float4*)(W + (size_t)d1 * DD))[tid];
    else           ((float4*)w2s)[tid - 512] = ((const float4*)(W + (size_t)d2 * DD))[tid - 512];
    __syncthreads();

    // each thread owns h0 = 2*tid, h1 = 2*tid+1
    const int h0 = tid * 2, h1 = h0 + 1;
    const int z0 = zsh[h0], z1 = zsh[h1];
    const int p0 = (h0 > 0) ? zsh[h0 - 1] + NN : 0;
    const int p1 = z0 + NN;

    float s0 = w1s[z0] + w2s[z0];
    if (h0 > 0) s0 += w1s[p0] + w2s[p0];
    float s1 = w1s[z1] + w2s[z1] + w1s[p1] + w2s[p1];

    // block max: wave shuffle + 16-entry LDS
    float m = fmaxf(s0, s1);
#pragma unroll
    for (int off = 32; off > 0; off >>= 1) m = fmaxf(m, __shfl_xor(m, off));
    if (lane == 0) red[wid] = m;
    __syncthreads();
    float mx = red[0];
#pragma unroll
    for (int i = 1; i < 16; ++i) mx = fmaxf(mx, red[i]);

    const float e0 = __expf(s0 - mx);
    const float e1 = __expf(s1 - mx);
    float t = e0 + e1;
#pragma unroll
    for (int off = 32; off > 0; off >>= 1) t += __shfl_xor(t, off);
    __syncthreads();                      // everyone done reading red (max)
    if (lane == 0) red[wid] = t;
    __syncthreads();
    float tot = red[0];
#pragma unroll
    for (int i = 1; i < 16; ++i) tot += red[i];
    const float inv = 1.f / tot;

    // scatter (unnormalized) straight from registers
    atomicAdd(&ws[z0], e0);
    if (h0 > 0) atomicAdd(&ws[p0], e0);
    atomicAdd(&ws[z1], e1);
    atomicAdd(&ws[p1], e1);
    __syncthreads();

    // write wsT[dg][b] float4 (read-optimal layout for phase2)
    if (tid < 512) {
        float4 o;
        o.x = ws[4 * tid + 0] * inv;
        o.y = ws[4 * tid + 1] * inv;
        o.z = ws[4 * tid + 2] * inv;
        o.w = ws[4 * tid + 3] * inv;
        ((float4*)wsT)[(size_t)tid * BB + b] = o;
    }
    if (tid == 0) { hdr[b] = d1; hdr[BB + b] = d2; }
}

// Phase 2: each 512-thread block computes output rows n0 = blockIdx.x and
// n1 = n0 + 512 for all 16 batches. Lane split: b = lane&15 (batch),
// q = lane>>4; slot = wave*4+q owns dgroups slot, slot+32, ...
// wsT reads: 16 consecutive float4 per 16-lane group (fully coalesced);
// V/F reads broadcast across the 16 b-lanes.
__global__ __launch_bounds__(512) void ot_phase2(const float* __restrict__ V,
                                                 const float* __restrict__ F,
                                                 const int* __restrict__ hdr,
                                                 const float* __restrict__ wsT,
                                                 float* __restrict__ out) {
    const int tid  = threadIdx.x;
    const int lane = tid & 63;
    const int w    = tid >> 6;           // 0..7
    const int bq   = lane & 15;          // batch
    const int q    = lane >> 4;          // 0..3
    const int slot = w * 4 + q;          // 0..31
    const int n0   = blockIdx.x;
    const int n1   = n0 + 512;

    const float4* __restrict__ V0 = (const float4*)(V + (size_t)n0 * DD);
    const float4* __restrict__ F0 = (const float4*)(F + (size_t)n0 * DD);
    const float4* __restrict__ V1 = (const float4*)(V + (size_t)n1 * DD);
    const float4* __restrict__ F1 = (const float4*)(F + (size_t)n1 * DD);
    const float4* __restrict__ WS = (const float4*)wsT;

    float a0 = 0.f, f0 = 0.f, a1 = 0.f, f1 = 0.f;

#pragma unroll 4
    for (int it = 0; it < 16; ++it) {
        const int dg = it * 32 + slot;
        float4 s  = WS[(size_t)dg * BB + bq];
        float4 v0 = V0[dg];
        float4 g0 = F0[dg];
        float4 v1 = V1[dg];
        float4 g1 = F1[dg];
        a0 += v0.x * s.x + v0.y * s.y + v0.z * s.z + v0.w * s.w;
        f0 += g0.x * s.x + g0.y * s.y + g0.z * s.z + g0.w * s.w;
        a1 += v1.x * s.x + v1.y * s.y + v1.z * s.z + v1.w * s.w;
        f1 += g1.x * s.x + g1.y * s.y + g1.z * s.z + g1.w * s.w;
    }

    // reduce over q (lanes b, b+16, b+32, b+48)
#pragma unroll
    for (int off = 16; off <= 32; off <<= 1) {
        a0 += __shfl_xor(a0, off);
        f0 += __shfl_xor(f0, off);
        a1 += __shfl_xor(a1, off);
        f1 += __shfl_xor(f1, off);
    }

    __shared__ float red[4][8][BB];
    if (lane < 16) {
        red[0][w][bq] = a0;
        red[1][w][bq] = f0;
        red[2][w][bq] = a1;
        red[3][w][bq] = f1;
    }
    __syncthreads();

    if (tid < BB) {
        const int b = tid;
        float A0 = 0.f, Fv0 = 0.f, A1 = 0.f, Fv1 = 0.f;
#pragma unroll
        for (int ww = 0; ww < 8; ++ww) {
            A0  += red[0][ww][b];
            Fv0 += red[1][ww][b];
            A1  += red[2][ww][b];
            Fv1 += red[3][ww][b];
        }
        const int e1i = hdr[b], e2i = hdr[BB + b];
        const float* __restrict__ Fr0 = F + (size_t)n0 * DD;
        const float* __restrict__ Fr1 = F + (size_t)n1 * DD;
        Fv0 += Fr0[e1i] + Fr0[e2i];
        Fv1 += Fr1[e1i] + Fr1[e2i];
        out[(size_t)b * NN + n0]            = A0 + Fv0;
        out[(size_t)(BB + b) * NN + n0]     = A0;
        out[(size_t)(2 * BB + b) * NN + n0] = Fv0;
        out[(size_t)b * NN + n1]            = A1 + Fv1;
        out[(size_t)(BB + b) * NN + n1]     = A1;
        out[(size_t)(2 * BB + b) * NN + n1] = Fv1;
    }
}

extern "C" void kernel_launch(void* const* d_in, const int* in_sizes, int n_in,
                              void* d_out, int out_size, void* d_ws, size_t ws_size,
                              hipStream_t stream) {
    const int*   z     = (const int*)d_in[0];
    const float* F_mat = (const float*)d_in[1];
    const float* V     = (const float*)d_in[2];
    const float* W     = (const float*)d_in[3];
    float* out = (float*)d_out;

    int*   hdr = (int*)d_ws;
    float* wsT = (float*)((char*)d_ws + 128);

    ot_phase1<<<BB, 1024, 0, stream>>>(z, W, hdr, wsT);
    ot_phase2<<<NN / 2, 512, 0, stream>>>(V, F_mat, hdr, wsT, out);
}